// Round 1
// baseline (111709.583 us; speedup 1.0000x reference)
//
#include <hip/hip_runtime.h>

// GRU scan T=512, B=128, H=512 fp32 — v3: single persistent cooperative kernel.
//
// v2 ran 512 dependent launches at 25.6 us/step vs a ~2.6 us/step VALU floor.
// Gap = per-step weight re-reads from L2 (384 global loads/lane, ~200 cy, only
// 2 waves/SIMD) + 512x launch/tail overhead. v3:
//  - ONE cooperative kernel; 512 steps internally, device-wide monotonic
//    atomic barrier (counter in d_ws, release/acquire fences for XCD L2s).
//  - Weights live in REGISTERS for the whole kernel: lane (w,kg,jl) owns
//    W[k-slice of 32][j0+jl][3 gates] = 96 VGPR. Zero steady-state W traffic.
//  - Per step only x_t, h_{t-1} move: coalesced f4 staging to LDS, read back
//    as 64B-contiguous f4 (kg spans one cache-line quad -> conflict-free).
//  - 8 waves: w0-3 h@Wh K-slices, w4-7 x@Wi K-slices; 1536 fmacs/lane/step.
//  - K-split partials -> f4 LDS reduction (stride-13 pad) overlaid on the
//    dead X/H tiles; 110 KB dynamic LDS -> exactly 1 wg/CU x 256 CUs.
//  - x[t+1] L2-prefetch overlapped with reduction + barrier wait.
// Predicted: ~4.5-6 us/step -> dur_us 13118 -> ~2500-3500.

#define TT 512
#define BB 128
#define HH 512
#define H3 1536
#define NWG 256
#define NTHR 512

#define LDS_FLOATS 28160
#define LDS_BYTES  (LDS_FLOATS * 4)   // 112640 B <= 160 KiB
// float layout: Xs [0,8192) ; Hs [8192,16384) ; red (f4) overlays [0,26624) ;
//               sums [26624,28160)

__global__ __launch_bounds__(NTHR, 2) void gru_scan(
    const float* __restrict__ x,
    const float* __restrict__ h0,
    const float* __restrict__ Wi,
    const float* __restrict__ bi,
    const float* __restrict__ Wh,
    const float* __restrict__ bhn,
    float* out,
    unsigned int* __restrict__ bar)
{
  extern __shared__ float lds[];
  float*  Xs   = lds;
  float*  Hs   = lds + 8192;
  float4* red  = reinterpret_cast<float4*>(lds);
  float*  sums = lds + 26624;

  const int tid = threadIdx.x;
  const int n   = blockIdx.x;
  const int jt  = n & 31;            // 32 j-tiles of 16 cols
  const int bt  = n >> 5;            // 8 b-tiles of 16 rows
  const int j0  = jt * 16;
  const int b0  = bt * 16;

  const int w   = tid >> 6;          // wave 0..7 ; 0-3 -> h@Wh, 4-7 -> x@Wi
  const int kg  = (tid >> 4) & 3;
  const int jl  = tid & 15;
  const int kbase = (w & 3) * 128;   // K-slice of 128 per wave (per matrix)
  const bool isH = (w < 4);

  // ---- weights to registers: 96 VGPR/lane, loaded once for all 512 steps.
  // lane covers k = kbase + m*16 + kg*4 + kk (m 0..7, kk 0..3), col j0+jl, 3 gates.
  float wreg[8][4][3];
  {
    const float* __restrict__ W = isH ? Wh : Wi;
    #pragma unroll
    for (int m = 0; m < 8; ++m)
      #pragma unroll
      for (int kk = 0; kk < 4; ++kk) {
        const int k = kbase + m * 16 + kg * 4 + kk;
        #pragma unroll
        for (int g = 0; g < 3; ++g)
          wreg[m][kk][g] = W[(size_t)k * H3 + g * HH + j0 + jl];
      }
  }

  float* ys = out + BB * HH;

  // per-epilogue-thread constants hoisted out of the t-loop
  float bir = 0.f, biz = 0.f, bin = 0.f, bhnv = 0.f;
  if (tid < 256) {
    const int jj = j0 + (tid & 15);
    bir  = bi[jj];
    biz  = bi[jj + HH];
    bin  = bi[jj + 2 * HH];
    bhnv = bhn[jj];
  }

  for (int t = 0; t < TT; ++t) {
    const float* __restrict__ xt = x + (size_t)t * BB * HH;
    const float* hp = t ? (ys + (size_t)(t - 1) * BB * HH) : h0;

    // ---- stage x_t and h_{t-1} tiles (16 x 512 f each), coalesced f4 ----
    #pragma unroll
    for (int i = 0; i < 4; ++i) {
      const int idx = tid + i * NTHR;
      const int r = idx >> 7;        // 0..15
      const int c = idx & 127;       // f4 col
      const float4 xv = ((const float4*)(xt + (size_t)(b0 + r) * HH))[c];
      const float4 hv = ((const float4*)(hp + (size_t)(b0 + r) * HH))[c];
      *(float4*)&Xs[r * 512 + c * 4] = xv;
      *(float4*)&Hs[r * 512 + c * 4] = hv;
    }
    __syncthreads();

    // ---- GEMM slice: 1536 fmacs/lane, weights from registers -----------
    float acc[16][3];
    #pragma unroll
    for (int b = 0; b < 16; ++b)
      #pragma unroll
      for (int g = 0; g < 3; ++g) acc[b][g] = 0.f;

    {
      const float* __restrict__ S = isH ? Hs : Xs;
      #pragma unroll
      for (int m = 0; m < 8; ++m) {
        // per read instr: 4 distinct f4 (kg*16B) = one 64B line, 16-dup broadcast
        const float* Sm = S + kbase + m * 16 + kg * 4;
        #pragma unroll
        for (int bq = 0; bq < 4; ++bq) {
          const float4 v0 = *(const float4*)(Sm + (bq * 4 + 0) * 512);
          const float4 v1 = *(const float4*)(Sm + (bq * 4 + 1) * 512);
          const float4 v2 = *(const float4*)(Sm + (bq * 4 + 2) * 512);
          const float4 v3 = *(const float4*)(Sm + (bq * 4 + 3) * 512);
          #pragma unroll
          for (int g = 0; g < 3; ++g) {
            acc[bq*4+0][g] += v0.x*wreg[m][0][g] + v0.y*wreg[m][1][g] + v0.z*wreg[m][2][g] + v0.w*wreg[m][3][g];
            acc[bq*4+1][g] += v1.x*wreg[m][0][g] + v1.y*wreg[m][1][g] + v1.z*wreg[m][2][g] + v1.w*wreg[m][3][g];
            acc[bq*4+2][g] += v2.x*wreg[m][0][g] + v2.y*wreg[m][1][g] + v2.z*wreg[m][2][g] + v2.w*wreg[m][3][g];
            acc[bq*4+3][g] += v3.x*wreg[m][0][g] + v3.y*wreg[m][1][g] + v3.z*wreg[m][2][g] + v3.w*wreg[m][3][g];
          }
        }
      }
    }
    __syncthreads();   // Xs/Hs dead -> red may overlay them

    // ---- L2-prefetch next x tile (overlaps reduction + barrier wait) ----
    if (t + 1 < TT) {
      const float* xn = x + (size_t)(t + 1) * BB * HH;
      #pragma unroll
      for (int i = 0; i < 4; ++i) {
        const int idx = tid + i * NTHR;
        const int r = idx >> 7;
        const int c = idx & 127;
        const float4 v = ((const float4*)(xn + (size_t)(b0 + r) * HH))[c];
        asm volatile("" :: "v"(v.x), "v"(v.y), "v"(v.z), "v"(v.w));
      }
    }

    // ---- write K-split partials: 12 f4/lane, stride 13 breaks conflicts --
    {
      float4* rp = red + (size_t)(((w * 4 + kg) * 16) + jl) * 13;
      #pragma unroll
      for (int bq = 0; bq < 4; ++bq)
        #pragma unroll
        for (int g = 0; g < 3; ++g)
          rp[bq * 3 + g] = make_float4(acc[bq*4+0][g], acc[bq*4+1][g],
                                       acc[bq*4+2][g], acc[bq*4+3][g]);
    }
    __syncthreads();

    // ---- reduce the 16 partials per matrix (384 active threads) ---------
    {
      const int pm  = tid >> 8;        // 0 = h-side, 1 = x-side
      const int pjl = (tid >> 4) & 15;
      const int pg  = (tid >> 2) & 3;
      const int pbq = tid & 3;
      if (pg < 3) {
        float4 s = make_float4(0.f, 0.f, 0.f, 0.f);
        #pragma unroll
        for (int ww = 0; ww < 4; ++ww)
          #pragma unroll
          for (int k2 = 0; k2 < 4; ++k2) {
            const float4 v = red[(size_t)((((pm*4+ww)*4 + k2) * 16) + pjl) * 13 + pbq * 3 + pg];
            s.x += v.x; s.y += v.y; s.z += v.z; s.w += v.w;
          }
        *(float4*)&sums[(size_t)(((pm * 16 + pjl) * 3) + pg) * 16 + pbq * 4] = s;
      }
    }
    __syncthreads();

    // ---- fused gate epilogue + store h_t (256 threads, one (b,j) each) --
    if (tid < 256) {
      const int eb  = tid >> 4;
      const int jl2 = tid & 15;
      const int jj  = j0 + jl2;
      const float ghr = sums[(jl2*3 + 0)*16 + eb];
      const float ghz = sums[(jl2*3 + 1)*16 + eb];
      const float ghn = sums[(jl2*3 + 2)*16 + eb];
      const float gir = sums[((16 + jl2)*3 + 0)*16 + eb];
      const float giz = sums[((16 + jl2)*3 + 1)*16 + eb];
      const float gin = sums[((16 + jl2)*3 + 2)*16 + eb];

      const float gr = gir + ghr + bir;
      const float gz = giz + ghz + biz;
      const float r  = 1.f / (1.f + __expf(-gr));
      const float z  = 1.f / (1.f + __expf(-gz));
      const float pre = gin + bin + r * (ghn + bhnv);
      const float e2 = __expf(2.f * pre);
      const float nn = 1.f - 2.f / (e2 + 1.f);
      const float hpv = hp[(size_t)(b0 + eb) * HH + jj];   // L2-hot
      const float h = (1.f - z) * nn + z * hpv;

      const size_t o = (size_t)(b0 + eb) * HH + jj;
      ys[(size_t)t * BB * HH + o] = h;
      if (t == TT - 1) out[o] = h;
    }

    // ---- device-wide barrier: monotonic counter in d_ws -----------------
    if (t + 1 < TT) {
      __syncthreads();               // all stores of this wg issued & drained
      if (tid == 0) {
        __threadfence();             // release: write back XCD L2 (h_t visible)
        atomicAdd(bar, 1u);          // device-scope
        const unsigned int target = (unsigned int)NWG * (unsigned int)(t + 1);
        while (__hip_atomic_load(bar, __ATOMIC_ACQUIRE, __HIP_MEMORY_SCOPE_AGENT) < target)
          __builtin_amdgcn_s_sleep(2);
        __threadfence();             // acquire: invalidate L1/L2 before reads
      }
      __syncthreads();
    }
  }
}

extern "C" void kernel_launch(void* const* d_in, const int* in_sizes, int n_in,
                              void* d_out, int out_size, void* d_ws, size_t ws_size,
                              hipStream_t stream) {
  const float* x   = (const float*)d_in[0];  // [T,B,H]
  const float* h0  = (const float*)d_in[1];  // [B,H]
  const float* Wi  = (const float*)d_in[2];  // [H,3H]
  const float* bi  = (const float*)d_in[3];  // [3H]
  const float* Wh  = (const float*)d_in[4];  // [H,3H]
  const float* bhn = (const float*)d_in[5];  // [H]
  float* out = (float*)d_out;                // [B,H] final + [T,B,H] ys
  unsigned int* bar = (unsigned int*)d_ws;

  static bool attr_done = false;
  if (!attr_done) {
    hipFuncSetAttribute(reinterpret_cast<const void*>(gru_scan),
                        hipFuncAttributeMaxDynamicSharedMemorySize, LDS_BYTES);
    attr_done = true;
  }

  hipMemsetAsync(d_ws, 0, 64, stream);       // reset barrier counter each replay

  void* args[] = {(void*)&x, (void*)&h0, (void*)&Wi, (void*)&bi,
                  (void*)&Wh, (void*)&bhn, (void*)&out, (void*)&bar};
  hipLaunchCooperativeKernel(reinterpret_cast<const void*>(gru_scan),
                             dim3(NWG), dim3(NTHR), args, LDS_BYTES, stream);
}